// Round 11
// baseline (28.487 us; speedup 1.0000x reference)
//
#include <hip/hip_runtime.h>
#include <hip/hip_bf16.h>

// SpeakerEmbedder: token histogram (bag-of-words mean) -> 3-layer MLP -> L2 normalize.
// B=64, T=16384, VOCAB=1024, HIDDEN=512, EMBED=256. All math in fp32.
//
// Round-10: r9 proved communication-free full fusion hits a per-CU L2 wall
// (every block streams all 3.67MB of W through one CU's ~144GB/s L2 port ->
// >=25us). So j-partitioned phases + flags are required. r8's flag protocol
// was correct but its flags shared cache lines (16 dwords on ONE 64B line ->
// ~500 serialized MALL RMW/poll ops per handoff). THIS ROUND: identical to
// r8 except every flag lives on its own 128-B line.
// Handoff protocol (unchanged from r8):
//   producer: sc1 (agent-scope) stores -> s_waitcnt vmcnt(0) -> __syncthreads
//             -> thread0 fetch_add(flag).
//   consumer: thread0 spins on flag -> __syncthreads -> plain cached loads
//             (first touch post-flag misses L2, refills fresh from MALL).

#define VOCAB 1024
#define HIDDEN 512
#define EMBED 256
#define TOK_T 16384
#define BATCH 64
#define HSEG 4  // histogram segments per row (all 256 blocks do hist)

#define AGENT __HIP_MEMORY_SCOPE_AGENT

struct alignas(128) Flag { unsigned v; };  // one flag per 128-B line (sizeof==128)

__device__ __forceinline__ void st_u32(unsigned* p, unsigned v) {
    __hip_atomic_store(p, v, __ATOMIC_RELAXED, AGENT);  // sc1: through to MALL
}
__device__ __forceinline__ void st_f32(float* p, float v) {
    __hip_atomic_store(p, v, __ATOMIC_RELAXED, AGENT);
}

// All threads arrive; thread0 publishes one arrival on flag.
__device__ __forceinline__ void signal(Flag* flag) {
    asm volatile("s_waitcnt vmcnt(0)" ::: "memory");  // stores acked at coherence point
    __syncthreads();
    if (threadIdx.x == 0) __hip_atomic_fetch_add(&flag->v, 1u, __ATOMIC_RELAXED, AGENT);
}
__device__ __forceinline__ void wait_flag(const Flag* flag, unsigned target) {
    if (threadIdx.x == 0) {
        while (__hip_atomic_load(&flag->v, __ATOMIC_RELAXED, AGENT) != target)
            __builtin_amdgcn_s_sleep(1);
    }
    __syncthreads();  // orders all waves' subsequent loads after the flag
}

#define XSIDX(k) ((k) + ((k) >> 6))  // LDS pad: k-groups land on distinct banks

struct SMemDense {
    float4 xs4[VOCAB + VOCAB / 64];  // x transposed: [k][4 rows], padded
    float part[16][4][32];           // [kg][r][jl]
};
union SMem {
    unsigned cnt[VOCAB];
    SMemDense d;
};

// ---------------------------------------------------------------------------
// Row-blocked dense phase. Block tile: 4 rows x 32 cols; 256 thr = 16 kg x
// 16 jt; thread tile 4 rows x 2 cols. Staging: plain cached coalesced loads.
// Output: sc1 stores.
// ---------------------------------------------------------------------------
template <int K, int OUT, bool RELU, bool SSQ>
__device__ __forceinline__ void dense_phase(SMem& sm, int rg, int jw,
                                            const float* __restrict__ in,
                                            const float* __restrict__ W,
                                            const float* __restrict__ bias,
                                            float* __restrict__ outp,
                                            float* __restrict__ ssqp) {
    constexpr int KG = 16;
    constexpr int KC = K / KG;
    constexpr int JW = OUT / 32;
    const int b0 = rg * 4;
    const int tid = threadIdx.x;

    // ---- stage x (4 rows) transposed into LDS (plain cached loads) ----
    for (int k = tid; k < K; k += 256) {
        float4 v;
        v.x = in[(size_t)(b0 + 0) * K + k];
        v.y = in[(size_t)(b0 + 1) * K + k];
        v.z = in[(size_t)(b0 + 2) * K + k];
        v.w = in[(size_t)(b0 + 3) * K + k];
        sm.d.xs4[XSIDX(k)] = v;
    }
    __syncthreads();

    // ---- compute: thread (kg, jt) -> 4 rows x 2 cols over its K-chunk ----
    const int jt = tid & 15;
    const int kg = tid >> 4;
    const float* __restrict__ w = W + (size_t)(kg * KC) * OUT + jw * 32 + jt * 2;

    float2 acc0 = {0.f, 0.f}, acc1 = {0.f, 0.f}, acc2 = {0.f, 0.f}, acc3 = {0.f, 0.f};
#pragma unroll 8
    for (int ks = 0; ks < KC; ++ks) {
        const int k = kg * KC + ks;
        const float4 xv = sm.d.xs4[XSIDX(k)];                       // conflict-free bcast
        const float2 wv = *(const float2*)(w + (size_t)ks * OUT);   // cached, coalesced
        acc0.x = fmaf(xv.x, wv.x, acc0.x); acc0.y = fmaf(xv.x, wv.y, acc0.y);
        acc1.x = fmaf(xv.y, wv.x, acc1.x); acc1.y = fmaf(xv.y, wv.y, acc1.y);
        acc2.x = fmaf(xv.z, wv.x, acc2.x); acc2.y = fmaf(xv.z, wv.y, acc2.y);
        acc3.x = fmaf(xv.w, wv.x, acc3.x); acc3.y = fmaf(xv.w, wv.y, acc3.y);
    }

    *(float2*)&sm.d.part[kg][0][jt * 2] = acc0;
    *(float2*)&sm.d.part[kg][1][jt * 2] = acc1;
    *(float2*)&sm.d.part[kg][2][jt * 2] = acc2;
    *(float2*)&sm.d.part[kg][3][jt * 2] = acc3;
    __syncthreads();

    // ---- reduce 16 k-groups, bias, activation, sc1 store ----
    if (tid < 128) {
        const int r = tid >> 5;   // 0..3
        const int jl = tid & 31;  // 0..31
        float s = bias[jw * 32 + jl];
#pragma unroll
        for (int g = 0; g < KG; ++g) s += sm.d.part[g][r][jl];
        if (RELU) s = fmaxf(s, 0.0f);
        st_f32(&outp[(size_t)(b0 + r) * OUT + jw * 32 + jl], s);
        if constexpr (SSQ) {
            float s2 = s * s;
#pragma unroll
            for (int off = 16; off > 0; off >>= 1) s2 += __shfl_down(s2, off, 32);
            if (jl == 0) st_f32(&ssqp[(size_t)(b0 + r) * JW + jw], s2);
        }
    }
}

// ---------------------------------------------------------------------------
// Single fused kernel; grid MUST be 256 x 256 (all blocks co-resident: 1/CU).
// ---------------------------------------------------------------------------
__global__ __launch_bounds__(256) void fused_kernel(const int* __restrict__ tokens,
                                                    const float* __restrict__ W1,
                                                    const float* __restrict__ b1,
                                                    const float* __restrict__ W2,
                                                    const float* __restrict__ b2,
                                                    const float* __restrict__ W3,
                                                    const float* __restrict__ b3,
                                                    float* __restrict__ out,
                                                    unsigned* __restrict__ counts,
                                                    float* __restrict__ h1,
                                                    float* __restrict__ h2,
                                                    float* __restrict__ emb,
                                                    float* __restrict__ ssqp,
                                                    Flag* __restrict__ flagH,
                                                    Flag* __restrict__ flag1,
                                                    Flag* __restrict__ flag2,
                                                    Flag* __restrict__ flag3) {
    __shared__ SMem sm;
    const int blk = blockIdx.x;
    const int tid = threadIdx.x;

    // ===== Phase 1: token histograms (64 rows x 4 segments = 256 blocks) =====
    {
        const int b = blk >> 2;
        const int seg = blk & 3;
#pragma unroll
        for (int i = 0; i < VOCAB / 256; ++i) sm.cnt[tid + 256 * i] = 0u;
        __syncthreads();

        const int4* __restrict__ t4 =
            reinterpret_cast<const int4*>(tokens + (size_t)b * TOK_T + seg * (TOK_T / HSEG));
#pragma unroll
        for (int i = 0; i < TOK_T / HSEG / 4 / 256; ++i) {  // 4 iterations
            int4 v = t4[i * 256 + tid];
            atomicAdd(&sm.cnt[v.x & (VOCAB - 1)], 1u);
            atomicAdd(&sm.cnt[v.y & (VOCAB - 1)], 1u);
            atomicAdd(&sm.cnt[v.z & (VOCAB - 1)], 1u);
            atomicAdd(&sm.cnt[v.w & (VOCAB - 1)], 1u);
        }
        __syncthreads();

        unsigned* __restrict__ row = counts + ((size_t)b * HSEG + seg) * VOCAB;
#pragma unroll
        for (int i = 0; i < 4; ++i) st_u32(&row[tid * 4 + i], sm.cnt[tid * 4 + i]);
        signal(&flagH[b]);
    }

    // ===== Phase 2: dense1 (1024->512, relu); pooled fused from counts =====
    {
        const int rg = blk >> 4;  // 16 rowgroups
        const int jw = blk & 15;  // 16 j-windows
        const int b0 = rg * 4;
        if (tid == 0) {
#pragma unroll
            for (int r = 0; r < 4; ++r)
                while (__hip_atomic_load(&flagH[b0 + r].v, __ATOMIC_RELAXED, AGENT) != HSEG)
                    __builtin_amdgcn_s_sleep(1);
        }
        __syncthreads();

        // stage pooled (counts segsum / T) transposed into LDS (plain loads)
        {
            const float invT = 1.0f / (float)TOK_T;
#pragma unroll
            for (int ko = 0; ko < 4; ++ko) {
                const int k = tid + 256 * ko;
                float4 v;
#pragma unroll
                for (int r = 0; r < 4; ++r) {
                    const unsigned* __restrict__ cr = counts + (size_t)(b0 + r) * HSEG * VOCAB;
                    unsigned s = cr[k] + cr[k + VOCAB] + cr[k + 2 * VOCAB] + cr[k + 3 * VOCAB];
                    (&v.x)[r] = (float)s * invT;
                }
                sm.d.xs4[XSIDX(k)] = v;
            }
        }
        __syncthreads();

        constexpr int K = VOCAB, OUT = HIDDEN, KG = 16, KC = K / KG;
        const int jt = tid & 15;
        const int kg = tid >> 4;
        const float* __restrict__ w = W1 + (size_t)(kg * KC) * OUT + jw * 32 + jt * 2;
        float2 acc0 = {0.f, 0.f}, acc1 = {0.f, 0.f}, acc2 = {0.f, 0.f}, acc3 = {0.f, 0.f};
#pragma unroll 8
        for (int ks = 0; ks < KC; ++ks) {
            const int k = kg * KC + ks;
            const float4 xv = sm.d.xs4[XSIDX(k)];
            const float2 wv = *(const float2*)(w + (size_t)ks * OUT);
            acc0.x = fmaf(xv.x, wv.x, acc0.x); acc0.y = fmaf(xv.x, wv.y, acc0.y);
            acc1.x = fmaf(xv.y, wv.x, acc1.x); acc1.y = fmaf(xv.y, wv.y, acc1.y);
            acc2.x = fmaf(xv.z, wv.x, acc2.x); acc2.y = fmaf(xv.z, wv.y, acc2.y);
            acc3.x = fmaf(xv.w, wv.x, acc3.x); acc3.y = fmaf(xv.w, wv.y, acc3.y);
        }
        *(float2*)&sm.d.part[kg][0][jt * 2] = acc0;
        *(float2*)&sm.d.part[kg][1][jt * 2] = acc1;
        *(float2*)&sm.d.part[kg][2][jt * 2] = acc2;
        *(float2*)&sm.d.part[kg][3][jt * 2] = acc3;
        __syncthreads();
        if (tid < 128) {
            const int r = tid >> 5;
            const int jl = tid & 31;
            float s = b1[jw * 32 + jl];
#pragma unroll
            for (int g = 0; g < KG; ++g) s += sm.d.part[g][r][jl];
            st_f32(&h1[(size_t)(b0 + r) * OUT + jw * 32 + jl], fmaxf(s, 0.0f));
        }
        signal(&flag1[rg]);
    }

    // ===== Phase 3: dense2 (512->512, relu) =====
    {
        const int rg = blk >> 4;
        const int jw = blk & 15;
        wait_flag(&flag1[rg], 16);
        dense_phase<HIDDEN, HIDDEN, true, false>(sm, rg, jw, h1, W2, b2, h2, nullptr);
        signal(&flag2[rg]);
    }

    // ===== Phase 4: dense3 (512->256) + ssq partials (blocks 0-127) =====
    if (blk < (BATCH / 4) * (EMBED / 32)) {
        const int rg = blk >> 3;  // 16 rowgroups
        const int jw = blk & 7;   // 8 j-windows
        wait_flag(&flag2[rg], 16);
        dense_phase<HIDDEN, EMBED, false, true>(sm, rg, jw, h2, W3, b3, emb, ssqp);
        signal(&flag3[rg]);
    }

    // ===== Phase 5: L2 normalize (blocks 0-63, one row each) =====
    if (blk < BATCH) {
        const int b = blk;
        wait_flag(&flag3[b >> 2], 8);
        float total = 0.0f;
#pragma unroll
        for (int i = 0; i < EMBED / 32; ++i) total += ssqp[(size_t)b * (EMBED / 32) + i];
        const float v = emb[(size_t)b * EMBED + tid];
        out[(size_t)b * EMBED + tid] = v / fmaxf(sqrtf(total), 1e-12f);  // F.normalize eps
    }
}

// ---------------------------------------------------------------------------
// Launch: 14-KB flag-clear memset + ONE regular kernel launch.
// ---------------------------------------------------------------------------
extern "C" void kernel_launch(void* const* d_in, const int* in_sizes, int n_in,
                              void* d_out, int out_size, void* d_ws, size_t ws_size,
                              hipStream_t stream) {
    const int*   tokens = (const int*)d_in[0];   // [64,16384], values in [0,1024)
    const float* W1     = (const float*)d_in[1]; // [1024,512]
    const float* b1     = (const float*)d_in[2]; // [512]
    const float* W2     = (const float*)d_in[3]; // [512,512]
    const float* b2     = (const float*)d_in[4]; // [512]
    const float* W3     = (const float*)d_in[5]; // [512,256]
    const float* b3     = (const float*)d_in[6]; // [256]
    float*       out    = (float*)d_out;         // [64,256]

    // Workspace layout (byte offsets; all regions fully rewritten every call).
    uint8_t* base = (uint8_t*)d_ws;
    unsigned* counts = (unsigned*)(base);             // [64][4][1024] u32 = 1 MB
    float*    h1     = (float*)(base + 0x100000);     // [64][512] = 128 KB
    float*    h2     = (float*)(base + 0x120000);     // [64][512] = 128 KB
    float*    emb    = (float*)(base + 0x140000);     // [64][256] = 64 KB
    float*    ssqp   = (float*)(base + 0x150000);     // [64][8]   = 2 KB
    Flag*     flagH  = (Flag*)(base + 0x150800);      // 64 x 128 B
    Flag*     flag1  = flagH + BATCH;                 // 16 x 128 B
    Flag*     flag2  = flag1 + 16;                    // 16 x 128 B
    Flag*     flag3  = flag2 + 16;                    // 16 x 128 B

    // Flags must start at 0 every call: 112 x 128 B = 14336 B.
    hipMemsetAsync((void*)flagH, 0, 112 * sizeof(Flag), stream);

    fused_kernel<<<256, 256, 0, stream>>>(tokens, W1, b1, W2, b2, W3, b3, out,
                                          counts, h1, h2, emb, ssqp,
                                          flagH, flag1, flag2, flag3);
}